// Round 1
// baseline (1717.015 us; speedup 1.0000x reference)
//
#include <hip/hip_runtime.h>
#include <math.h>

#define NXF 512
#define NPTS (NXF * NXF)   // 262144
#define NB 4
#define NT 256
#define NM 256

// ---------------------------------------------------------------------------
// Setup: zero both field buffers, build vel2 = ((dt*xp)/dx)^2 with the padded
// layout (outer 55-wide frame = 1e-6, bg=1.5 ring, x in [128,384)^2),
// and init the meas_id table to -1.
// ---------------------------------------------------------------------------
__global__ __launch_bounds__(256) void init_kernel(const float* __restrict__ x,
                                                   float* __restrict__ bufA,
                                                   float* __restrict__ bufB,
                                                   float* __restrict__ vel2,
                                                   int* __restrict__ meas_id) {
    int gid = blockIdx.x * blockDim.x + threadIdx.x;
    if (gid >= NB * NPTS) return;
    bufA[gid] = 0.0f;
    bufB[gid] = 0.0f;
    int b = gid >> 18;
    int idx = gid & (NPTS - 1);
    int i = idx >> 9;
    int j = idx & 511;
    float v;
    if (i < 55 || i >= 457 || j < 55 || j >= 457) {
        v = 1e-6f;
    } else if (i >= 128 && i < 384 && j >= 128 && j < 384) {
        v = x[b * 65536 + ((i - 128) << 8) + (j - 128)];
    } else {
        v = 1.5f;  // bg
    }
    // dt * xp / dx, then squared — mirror numpy f32 scalar promotion
    float a = (2e-05f * v) / 1e-04f;
    vel2[gid] = a * a;
    if (b == 0) meas_id[idx] = -1;
}

__global__ void scatter_kernel(const int* __restrict__ meas_flat,
                               int* __restrict__ meas_id) {
    int m = threadIdx.x;  // 256 threads
    meas_id[meas_flat[m]] = m;
}

// ---------------------------------------------------------------------------
// One time step: p = 2*p1 - p0 + vel2 * (nab_x + nab_y)  (periodic roll),
// then source injection at TRANS points (m % 4 == 0, se[m/4]) and
// measurement write at MEAS points — fused: the owning thread has the
// post-injection value in register.
// ---------------------------------------------------------------------------
__global__ __launch_bounds__(256) void step_kernel(const float* __restrict__ p0,
                                                   const float* __restrict__ p1,
                                                   const float* __restrict__ vel2,
                                                   const int* __restrict__ meas_id,
                                                   const float* __restrict__ src_tab,
                                                   const float* __restrict__ se,
                                                   float* __restrict__ pnew,
                                                   float* __restrict__ out,
                                                   int t) {
    int gid = blockIdx.x * blockDim.x + threadIdx.x;  // 0 .. 4*262144
    int b = gid >> 18;
    int idx = gid & (NPTS - 1);
    int i = idx >> 9;
    int j = idx & 511;
    const float* P1 = p1 + (b << 18);

    int row = i << 9;
    int rm1 = ((i - 1) & 511) << 9;
    int rm2 = ((i - 2) & 511) << 9;
    int rp1 = ((i + 1) & 511) << 9;
    int rp2 = ((i + 2) & 511) << 9;
    int jm1 = (j - 1) & 511;
    int jm2 = (j - 2) & 511;
    int jp1 = (j + 1) & 511;
    int jp2 = (j + 2) & 511;

    float c = P1[row | j];
    float nab_x = (-P1[rm2 | j] + 16.0f * P1[rm1 | j] - 30.0f * c
                   + 16.0f * P1[rp1 | j] - P1[rp2 | j]) * (1.0f / 12.0f);
    float nab_y = (-P1[row | jm2] + 16.0f * P1[row | jm1] - 30.0f * c
                   + 16.0f * P1[row | jp1] - P1[row | jp2]) * (1.0f / 12.0f);

    float pn = 2.0f * c - p0[gid] + vel2[gid] * (nab_x + nab_y);

    int mid = meas_id[idx];
    if (mid >= 0) {
        if ((mid & 3) == 0) {
            // SRC_COEF * src_j * se[m/4], f32 like the reference
            pn += 0.09000000000000002f * src_tab[t] * se[mid >> 2];
        }
        out[(b << 16) | (mid << 8) | t] = pn;
    }
    pnew[gid] = pn;
}

// ---------------------------------------------------------------------------
// Host launch
// ---------------------------------------------------------------------------
extern "C" void kernel_launch(void* const* d_in, const int* in_sizes, int n_in,
                              void* d_out, int out_size, void* d_ws, size_t ws_size,
                              hipStream_t stream) {
    const float* x  = (const float*)d_in[0];   // (4,1,256,256) fp32
    const float* se = (const float*)d_in[1];   // (64,) fp32
    float* out = (float*)d_out;                // (4,1,256,256) fp32 = [b][m][t]

    char* ws = (char*)d_ws;
    const size_t FIELD_BYTES = (size_t)NB * NPTS * sizeof(float);  // 4 MB
    float* bufA   = (float*)(ws);
    float* bufB   = (float*)(ws + FIELD_BYTES);
    float* vel2   = (float*)(ws + 2 * FIELD_BYTES);
    int*   measId = (int*)  (ws + 3 * FIELD_BYTES);                 // NPTS ints
    int*   dMeas  = (int*)  (ws + 3 * FIELD_BYTES + (size_t)NPTS * 4);
    float* dSrc   = (float*)(ws + 3 * FIELD_BYTES + (size_t)NPTS * 4 + NM * 4);

    // Host tables — double trig via glibc (bit-identical to numpy float64),
    // fp32 source wavelet mirroring numpy's float32 promotion rules.
    static int   h_meas[NM];
    static float h_src[NT];
    for (int m = 0; m < NM; ++m) {
        double theta = (2.0 * M_PI * (double)m) / 256.0;
        int mx = (int)(256.0 + 200.0 * cos(theta));  // trunc toward zero, like .astype(int)
        int my = (int)(256.0 + 200.0 * sin(theta));
        h_meas[m] = mx * NXF + my;
    }
    for (int t = 0; t < NT; ++t) {
        float tj  = (float)t * 2e-05f;
        float arg = (float)(2.0 * M_PI * 500.0) * tj;
        float d   = tj - 0.002f;
        float e   = -(d * d) / (float)(2.0 * 0.001 * 0.001);
        h_src[t]  = sinf(arg) * expf(e);
    }
    hipMemcpyAsync(dMeas, h_meas, sizeof(h_meas), hipMemcpyHostToDevice, stream);
    hipMemcpyAsync(dSrc,  h_src,  sizeof(h_src),  hipMemcpyHostToDevice, stream);

    init_kernel<<<(NB * NPTS + 255) / 256, 256, 0, stream>>>(x, bufA, bufB, vel2, measId);
    scatter_kernel<<<1, NM, 0, stream>>>(dMeas, measId);

    float* p0 = bufA;
    float* p1 = bufB;
    for (int t = 0; t < NT; ++t) {
        // p_new overwrites the dead p0 buffer; carry becomes (p1, p_new)
        step_kernel<<<NB * NPTS / 256, 256, 0, stream>>>(p0, p1, vel2, measId,
                                                         dSrc, se, p0, out, t);
        float* tmp = p0; p0 = p1; p1 = tmp;
    }
}